// Round 1
// baseline (335.454 us; speedup 1.0000x reference)
//
#include <hip/hip_runtime.h>
#include <math.h>

#define BB 16
#define TT 4096
#define DD 1024
#define HH 32

static constexpr float kEPS = 1e-6f;

// ---------------- Kernel 1: masked sum over T ----------------
// grid: (T/TCHUNK, B), block: 256 threads; each thread owns 4 consecutive d.
#define TCHUNK 64
__global__ __launch_bounds__(256) void reduce_kernel(
    const float* __restrict__ zr, const float* __restrict__ zi,
    const float* __restrict__ mask,
    float* __restrict__ arW, float* __restrict__ aiW, float* __restrict__ cntW) {
  const int b = blockIdx.y;
  const int t0 = blockIdx.x * TCHUNK;
  const int tid = threadIdx.x;
  const int d4 = tid * 4;

  float4 accR = make_float4(0.f, 0.f, 0.f, 0.f);
  float4 accI = make_float4(0.f, 0.f, 0.f, 0.f);
  float msum = 0.f;

  const size_t base = ((size_t)b * TT + t0) * DD + d4;
  const float* zrp = zr + base;
  const float* zip = zi + base;
  const float* mp = mask + (size_t)b * TT + t0;

  for (int t = 0; t < TCHUNK; ++t) {
    const float m = mp[t];
    msum += m;
    float4 r = *(const float4*)(zrp + (size_t)t * DD);
    float4 im = *(const float4*)(zip + (size_t)t * DD);
    accR.x += r.x * m; accR.y += r.y * m; accR.z += r.z * m; accR.w += r.w * m;
    accI.x += im.x * m; accI.y += im.y * m; accI.z += im.z * m; accI.w += im.w * m;
  }

  const int o = b * DD + d4;
  atomicAdd(&arW[o + 0], accR.x);
  atomicAdd(&arW[o + 1], accR.y);
  atomicAdd(&arW[o + 2], accR.z);
  atomicAdd(&arW[o + 3], accR.w);
  atomicAdd(&aiW[o + 0], accI.x);
  atomicAdd(&aiW[o + 1], accI.y);
  atomicAdd(&aiW[o + 2], accI.z);
  atomicAdd(&aiW[o + 3], accI.w);
  if (tid == 0) atomicAdd(&cntW[b], msum);
}

// ---------------- Kernel 2: per-(b,d) MLP ----------------
__global__ __launch_bounds__(256) void mlp_kernel(
    const float* __restrict__ arW, const float* __restrict__ aiW,
    const float* __restrict__ cntW,
    const float* __restrict__ W1m, const float* __restrict__ b1m,
    const float* __restrict__ W2m, const float* __restrict__ b2m,
    const float* __restrict__ W1p, const float* __restrict__ b1p,
    const float* __restrict__ W2p, const float* __restrict__ b2p,
    const float* __restrict__ mag_scale,
    float* __restrict__ anR, float* __restrict__ anI) {
  const int i = blockIdx.x * blockDim.x + threadIdx.x;
  if (i >= BB * DD) return;
  const int b = i >> 10;  // D = 1024

  const float count = fmaxf(cntW[b], 1.0f);
  const float Ar = arW[i] / count;
  const float Ai = aiW[i] / count;
  const float mag = sqrtf(Ar * Ar + Ai * Ai);
  const float log_mag = logf(mag + kEPS);
  const float inv_me = 1.0f / (mag + kEPS);
  const float pr = Ar * inv_me;
  const float pi = Ai * inv_me;

  // magnitude MLP: h_j = gelu(log_mag * W1m[j] + b1m[j]); md = sum h_j*W2m[j]+b2m
  float md = b2m[0];
  #pragma unroll
  for (int j = 0; j < HH; ++j) {
    float h = log_mag * W1m[j] + b1m[j];
    h = 0.5f * h * (1.0f + erff(h * 0.70710678118654752440f));
    md += h * W2m[j];
  }
  const float lmo = log_mag + mag_scale[0] * md;

  // phase MLP: hp_j = gelu(pr*W1p[j][0] + pi*W1p[j][1] + b1p[j])
  float pv0 = b2p[0];
  float pv1 = b2p[1];
  #pragma unroll
  for (int j = 0; j < HH; ++j) {
    float hp = pr * W1p[2 * j] + pi * W1p[2 * j + 1] + b1p[j];
    hp = 0.5f * hp * (1.0f + erff(hp * 0.70710678118654752440f));
    pv0 += hp * W2p[j];       // W2p[0][j]
    pv1 += hp * W2p[HH + j];  // W2p[1][j]
  }
  const float nrm = fmaxf(sqrtf(pv0 * pv0 + pv1 * pv1), 1e-12f);
  const float r_out = expf(lmo);
  anR[i] = r_out * pv0 / nrm;
  anI[i] = r_out * pv1 / nrm;
}

// ---------------- Kernel 3: broadcast add + write both planes ----------------
__global__ __launch_bounds__(256) void add_kernel(
    const float* __restrict__ zr, const float* __restrict__ zi,
    const float* __restrict__ anR, const float* __restrict__ anI,
    float* __restrict__ out) {
  const size_t N4 = (size_t)BB * TT * DD / 4;
  const size_t stride = (size_t)gridDim.x * blockDim.x;
  float* out0 = out;
  float* out1 = out + (size_t)BB * TT * DD;

  for (size_t i = (size_t)blockIdx.x * blockDim.x + threadIdx.x; i < N4; i += stride) {
    const size_t e = i * 4;
    const int b = (int)(e >> 22);      // T*D = 2^22
    const int d = (int)(e & (DD - 1)); // aligned to 4
    const int o = b * DD + d;
    float4 ar4 = *(const float4*)(anR + o);
    float4 ai4 = *(const float4*)(anI + o);
    float4 r = ((const float4*)zr)[i];
    float4 im = ((const float4*)zi)[i];
    r.x += ar4.x; r.y += ar4.y; r.z += ar4.z; r.w += ar4.w;
    im.x += ai4.x; im.y += ai4.y; im.z += ai4.z; im.w += ai4.w;
    ((float4*)out0)[i] = r;
    ((float4*)out1)[i] = im;
  }
}

extern "C" void kernel_launch(void* const* d_in, const int* in_sizes, int n_in,
                              void* d_out, int out_size, void* d_ws, size_t ws_size,
                              hipStream_t stream) {
  const float* zr = (const float*)d_in[0];
  const float* zi = (const float*)d_in[1];
  const float* mask = (const float*)d_in[2];
  const float* W1m = (const float*)d_in[3];
  const float* b1m = (const float*)d_in[4];
  const float* W2m = (const float*)d_in[5];
  const float* b2m = (const float*)d_in[6];
  const float* W1p = (const float*)d_in[7];
  const float* b1p = (const float*)d_in[8];
  const float* W2p = (const float*)d_in[9];
  const float* b2p = (const float*)d_in[10];
  const float* mag_scale = (const float*)d_in[11];

  float* ws = (float*)d_ws;
  float* arW = ws;                    // B*D = 16384
  float* aiW = ws + 16384;            // 16384
  float* cntW = ws + 32768;           // 16 (pad to 32)
  float* anR = ws + 32800;            // 16384
  float* anI = ws + 49184;            // 16384

  // zero the atomic accumulators (arW, aiW, cntW) every launch
  hipMemsetAsync(d_ws, 0, (32768 + 32) * sizeof(float), stream);

  dim3 g1(TT / TCHUNK, BB);
  reduce_kernel<<<g1, 256, 0, stream>>>(zr, zi, mask, arW, aiW, cntW);

  mlp_kernel<<<(BB * DD + 255) / 256, 256, 0, stream>>>(
      arW, aiW, cntW, W1m, b1m, W2m, b2m, W1p, b1p, W2p, b2p, mag_scale, anR, anI);

  add_kernel<<<2048, 256, 0, stream>>>(zr, zi, anR, anI, (float*)d_out);
}

// Round 3
// 313.278 us; speedup vs baseline: 1.0708x; 1.0708x over previous
//
#include <hip/hip_runtime.h>
#include <math.h>

#define BB 16
#define TT 4096
#define DD 1024
#define HH 32

static constexpr float kEPS = 1e-6f;

typedef float f32x4 __attribute__((ext_vector_type(4)));

// ---------------- Kernel 1: masked sum over T ----------------
// grid: (T/TCHUNK, B), block: 256 threads; each thread owns 4 consecutive d.
#define TCHUNK 64
__global__ __launch_bounds__(256) void reduce_kernel(
    const float* __restrict__ zr, const float* __restrict__ zi,
    const float* __restrict__ mask,
    float* __restrict__ arW, float* __restrict__ aiW, float* __restrict__ cntW) {
  const int b = blockIdx.y;
  const int t0 = blockIdx.x * TCHUNK;
  const int tid = threadIdx.x;
  const int d4 = tid * 4;

  f32x4 accR = (f32x4)(0.f);
  f32x4 accI = (f32x4)(0.f);
  float msum = 0.f;

  const size_t base = ((size_t)b * TT + t0) * DD + d4;
  const float* zrp = zr + base;
  const float* zip = zi + base;
  const float* mp = mask + (size_t)b * TT + t0;

  // unroll 4: 8 float4 loads in flight per iteration
  #pragma unroll 4
  for (int t = 0; t < TCHUNK; ++t) {
    const float m = mp[t];
    msum += m;
    f32x4 r = *(const f32x4*)(zrp + (size_t)t * DD);
    f32x4 im = *(const f32x4*)(zip + (size_t)t * DD);
    accR += r * m;
    accI += im * m;
  }

  const int o = b * DD + d4;
  atomicAdd(&arW[o + 0], accR.x);
  atomicAdd(&arW[o + 1], accR.y);
  atomicAdd(&arW[o + 2], accR.z);
  atomicAdd(&arW[o + 3], accR.w);
  atomicAdd(&aiW[o + 0], accI.x);
  atomicAdd(&aiW[o + 1], accI.y);
  atomicAdd(&aiW[o + 2], accI.z);
  atomicAdd(&aiW[o + 3], accI.w);
  if (tid == 0) atomicAdd(&cntW[b], msum);
}

// ---------------- Kernel 2: per-(b,d) MLP ----------------
__global__ __launch_bounds__(256) void mlp_kernel(
    const float* __restrict__ arW, const float* __restrict__ aiW,
    const float* __restrict__ cntW,
    const float* __restrict__ W1m, const float* __restrict__ b1m,
    const float* __restrict__ W2m, const float* __restrict__ b2m,
    const float* __restrict__ W1p, const float* __restrict__ b1p,
    const float* __restrict__ W2p, const float* __restrict__ b2p,
    const float* __restrict__ mag_scale,
    float* __restrict__ anR, float* __restrict__ anI) {
  const int i = blockIdx.x * blockDim.x + threadIdx.x;
  if (i >= BB * DD) return;
  const int b = i >> 10;  // D = 1024

  const float count = fmaxf(cntW[b], 1.0f);
  const float Ar = arW[i] / count;
  const float Ai = aiW[i] / count;
  const float mag = sqrtf(Ar * Ar + Ai * Ai);
  const float log_mag = logf(mag + kEPS);
  const float inv_me = 1.0f / (mag + kEPS);
  const float pr = Ar * inv_me;
  const float pi = Ai * inv_me;

  float md = b2m[0];
  #pragma unroll
  for (int j = 0; j < HH; ++j) {
    float h = log_mag * W1m[j] + b1m[j];
    h = 0.5f * h * (1.0f + erff(h * 0.70710678118654752440f));
    md += h * W2m[j];
  }
  const float lmo = log_mag + mag_scale[0] * md;

  float pv0 = b2p[0];
  float pv1 = b2p[1];
  #pragma unroll
  for (int j = 0; j < HH; ++j) {
    float hp = pr * W1p[2 * j] + pi * W1p[2 * j + 1] + b1p[j];
    hp = 0.5f * hp * (1.0f + erff(hp * 0.70710678118654752440f));
    pv0 += hp * W2p[j];       // W2p[0][j]
    pv1 += hp * W2p[HH + j];  // W2p[1][j]
  }
  const float nrm = fmaxf(sqrtf(pv0 * pv0 + pv1 * pv1), 1e-12f);
  const float r_out = expf(lmo);
  anR[i] = r_out * pv0 / nrm;
  anI[i] = r_out * pv1 / nrm;
}

// ---------------- Kernel 3: broadcast add + write both planes ----------------
// Walk in REVERSE so we start on the Z tail that K1 left resident in L3.
// nt loads (no pollution) + nt stores (no-allocate; don't evict resident Z).
__global__ __launch_bounds__(256) void add_kernel(
    const float* __restrict__ zr, const float* __restrict__ zi,
    const float* __restrict__ anR, const float* __restrict__ anI,
    float* __restrict__ out) {
  const size_t N4 = (size_t)BB * TT * DD / 4;
  const size_t stride = (size_t)gridDim.x * blockDim.x;
  float* out0 = out;
  float* out1 = out + (size_t)BB * TT * DD;

  const int rb = gridDim.x - 1 - blockIdx.x;  // reversed block order
  const size_t lane = (size_t)rb * blockDim.x + threadIdx.x;
  const long long nIter = (long long)((N4 + stride - 1) / stride);

  for (long long it = nIter - 1; it >= 0; --it) {
    const size_t i = (size_t)it * stride + lane;
    if (i >= N4) continue;
    const size_t e = i * 4;
    const int b = (int)(e >> 22);      // T*D = 2^22
    const int d = (int)(e & (DD - 1)); // aligned to 4
    const int o = b * DD + d;
    f32x4 ar4 = *(const f32x4*)(anR + o);
    f32x4 ai4 = *(const f32x4*)(anI + o);
    f32x4 r  = __builtin_nontemporal_load((const f32x4*)zr + i);
    f32x4 im = __builtin_nontemporal_load((const f32x4*)zi + i);
    r += ar4;
    im += ai4;
    __builtin_nontemporal_store(r, (f32x4*)out0 + i);
    __builtin_nontemporal_store(im, (f32x4*)out1 + i);
  }
}

extern "C" void kernel_launch(void* const* d_in, const int* in_sizes, int n_in,
                              void* d_out, int out_size, void* d_ws, size_t ws_size,
                              hipStream_t stream) {
  const float* zr = (const float*)d_in[0];
  const float* zi = (const float*)d_in[1];
  const float* mask = (const float*)d_in[2];
  const float* W1m = (const float*)d_in[3];
  const float* b1m = (const float*)d_in[4];
  const float* W2m = (const float*)d_in[5];
  const float* b2m = (const float*)d_in[6];
  const float* W1p = (const float*)d_in[7];
  const float* b1p = (const float*)d_in[8];
  const float* W2p = (const float*)d_in[9];
  const float* b2p = (const float*)d_in[10];
  const float* mag_scale = (const float*)d_in[11];

  float* ws = (float*)d_ws;
  float* arW = ws;                    // B*D = 16384
  float* aiW = ws + 16384;            // 16384
  float* cntW = ws + 32768;           // 16 (pad to 32)
  float* anR = ws + 32800;            // 16384
  float* anI = ws + 49184;            // 16384

  // zero the atomic accumulators (arW, aiW, cntW) every launch
  (void)hipMemsetAsync(d_ws, 0, (32768 + 32) * sizeof(float), stream);

  dim3 g1(TT / TCHUNK, BB);
  reduce_kernel<<<g1, 256, 0, stream>>>(zr, zi, mask, arW, aiW, cntW);

  mlp_kernel<<<(BB * DD + 255) / 256, 256, 0, stream>>>(
      arW, aiW, cntW, W1m, b1m, W2m, b2m, W1p, b1p, W2p, b2p, mag_scale, anR, anI);

  add_kernel<<<2048, 256, 0, stream>>>(zr, zi, anR, anI, (float*)d_out);
}

// Round 4
// 282.669 us; speedup vs baseline: 1.1867x; 1.1083x over previous
//
#include <hip/hip_runtime.h>
#include <math.h>

#define BB 16
#define TT 4096
#define DD 1024
#define HH 32
#define TCHUNK 64
#define NCHUNK (TT / TCHUNK)   // 64

static constexpr float kEPS = 1e-6f;

typedef float f32x4 __attribute__((ext_vector_type(4)));

// ---------------- Kernel 1: masked partial sums over T ----------------
// grid: (NCHUNK, B), 256 threads; thread owns 4 consecutive d (256*4 = D).
// Writes per-chunk partial sums (no atomics -> no memset needed).
__global__ __launch_bounds__(256) void reduce_kernel(
    const float* __restrict__ zr, const float* __restrict__ zi,
    const float* __restrict__ mask,
    float* __restrict__ partR, float* __restrict__ partI,
    float* __restrict__ cntP) {
  const int c = blockIdx.x;
  const int b = blockIdx.y;
  const int tid = threadIdx.x;
  const int d4 = tid * 4;

  f32x4 accR = (f32x4)(0.f);
  f32x4 accI = (f32x4)(0.f);
  float msum = 0.f;

  const size_t base = ((size_t)b * TT + (size_t)c * TCHUNK) * DD + d4;
  const float* zrp = zr + base;
  const float* zip = zi + base;
  const float* mp = mask + (size_t)b * TT + (size_t)c * TCHUNK;

  #pragma unroll 8
  for (int t = 0; t < TCHUNK; ++t) {
    const float m = mp[t];
    msum += m;
    f32x4 r  = *(const f32x4*)(zrp + (size_t)t * DD);
    f32x4 im = *(const f32x4*)(zip + (size_t)t * DD);
    accR += r * m;
    accI += im * m;
  }

  const size_t po = ((size_t)c * BB + b) * DD + d4;
  *(f32x4*)(partR + po) = accR;
  *(f32x4*)(partI + po) = accI;
  if (tid == 0) cntP[c * BB + b] = msum;
}

// ---------------- Kernel 2: reduce partials + per-(b,d) MLP ----------------
// grid: 64 blocks x 256 threads = 16384 = B*D. Each block spans one b.
__global__ __launch_bounds__(256) void mlp_kernel(
    const float* __restrict__ partR, const float* __restrict__ partI,
    const float* __restrict__ cntP,
    const float* __restrict__ W1m, const float* __restrict__ b1m,
    const float* __restrict__ W2m, const float* __restrict__ b2m,
    const float* __restrict__ W1p, const float* __restrict__ b1p,
    const float* __restrict__ W2p, const float* __restrict__ b2p,
    const float* __restrict__ mag_scale,
    float* __restrict__ anR, float* __restrict__ anI) {
  const int i = blockIdx.x * blockDim.x + threadIdx.x;
  const int b = i >> 10;   // D = 1024
  const int d = i & (DD - 1);

  __shared__ float cntS;
  if (threadIdx.x == 0) {
    float s = 0.f;
    for (int c = 0; c < NCHUNK; ++c) s += cntP[c * BB + b];
    cntS = s;
  }
  __syncthreads();

  float sR = 0.f, sI = 0.f;
  for (int c = 0; c < NCHUNK; ++c) {
    const size_t po = ((size_t)c * BB + b) * DD + d;
    sR += partR[po];
    sI += partI[po];
  }

  const float count = fmaxf(cntS, 1.0f);
  const float Ar = sR / count;
  const float Ai = sI / count;
  const float mag = sqrtf(Ar * Ar + Ai * Ai);
  const float log_mag = logf(mag + kEPS);
  const float inv_me = 1.0f / (mag + kEPS);
  const float pr = Ar * inv_me;
  const float pi = Ai * inv_me;

  float md = b2m[0];
  #pragma unroll
  for (int j = 0; j < HH; ++j) {
    float h = log_mag * W1m[j] + b1m[j];
    h = 0.5f * h * (1.0f + erff(h * 0.70710678118654752440f));
    md += h * W2m[j];
  }
  const float lmo = log_mag + mag_scale[0] * md;

  float pv0 = b2p[0];
  float pv1 = b2p[1];
  #pragma unroll
  for (int j = 0; j < HH; ++j) {
    float hp = pr * W1p[2 * j] + pi * W1p[2 * j + 1] + b1p[j];
    hp = 0.5f * hp * (1.0f + erff(hp * 0.70710678118654752440f));
    pv0 += hp * W2p[j];       // W2p[0][j]
    pv1 += hp * W2p[HH + j];  // W2p[1][j]
  }
  const float nrm = fmaxf(sqrtf(pv0 * pv0 + pv1 * pv1), 1e-12f);
  const float r_out = expf(lmo);
  anR[i] = r_out * pv0 / nrm;
  anI[i] = r_out * pv1 / nrm;
}

// ---------------- Kernel 3: broadcast add + write both planes ----------------
// SAME layout as K1 (grid (NCHUNK,B), thread owns 4 d) but t walked BACKWARD:
// K1 leaves the tail rows of each chunk MRU in L3 -> read those first.
// nt loads: hit if resident, don't allocate/evict on miss. nt stores: no-allocate.
__global__ __launch_bounds__(256) void add_kernel(
    const float* __restrict__ zr, const float* __restrict__ zi,
    const float* __restrict__ anR, const float* __restrict__ anI,
    float* __restrict__ out) {
  const int c = blockIdx.x;
  const int b = blockIdx.y;
  const int tid = threadIdx.x;
  const int d4 = tid * 4;

  const int o = b * DD + d4;
  const f32x4 ar4 = *(const f32x4*)(anR + o);
  const f32x4 ai4 = *(const f32x4*)(anI + o);

  const size_t base = ((size_t)b * TT + (size_t)c * TCHUNK) * DD + d4;
  const float* zrp = zr + base;
  const float* zip = zi + base;
  float* out0 = out + base;
  float* out1 = out + (size_t)BB * TT * DD + base;

  #pragma unroll 8
  for (int t = TCHUNK - 1; t >= 0; --t) {
    const size_t ro = (size_t)t * DD;
    f32x4 r  = __builtin_nontemporal_load((const f32x4*)(zrp + ro));
    f32x4 im = __builtin_nontemporal_load((const f32x4*)(zip + ro));
    r += ar4;
    im += ai4;
    __builtin_nontemporal_store(r, (f32x4*)(out0 + ro));
    __builtin_nontemporal_store(im, (f32x4*)(out1 + ro));
  }
}

extern "C" void kernel_launch(void* const* d_in, const int* in_sizes, int n_in,
                              void* d_out, int out_size, void* d_ws, size_t ws_size,
                              hipStream_t stream) {
  const float* zr = (const float*)d_in[0];
  const float* zi = (const float*)d_in[1];
  const float* mask = (const float*)d_in[2];
  const float* W1m = (const float*)d_in[3];
  const float* b1m = (const float*)d_in[4];
  const float* W2m = (const float*)d_in[5];
  const float* b2m = (const float*)d_in[6];
  const float* W1p = (const float*)d_in[7];
  const float* b1p = (const float*)d_in[8];
  const float* W2p = (const float*)d_in[9];
  const float* b2p = (const float*)d_in[10];
  const float* mag_scale = (const float*)d_in[11];

  float* ws = (float*)d_ws;
  float* partR = ws;                       // NCHUNK*B*D = 1048576
  float* partI = ws + 1048576;             // 1048576
  float* cntP  = ws + 2097152;             // NCHUNK*B = 1024
  float* anR   = ws + 2098176;             // 16384
  float* anI   = ws + 2114560;             // 16384

  dim3 g(NCHUNK, BB);
  reduce_kernel<<<g, 256, 0, stream>>>(zr, zi, mask, partR, partI, cntP);

  mlp_kernel<<<BB * DD / 256, 256, 0, stream>>>(
      partR, partI, cntP, W1m, b1m, W2m, b2m, W1p, b1p, W2p, b2p, mag_scale, anR, anI);

  add_kernel<<<g, 256, 0, stream>>>(zr, zi, anR, anI, (float*)d_out);
}